// Round 1
// 332.940 us; speedup vs baseline: 1.0062x; 1.0062x over previous
//
#include <hip/hip_runtime.h>

#define EMBED 64
#define BATCH 4096
#define G     8     // row-gathers in flight per wave batch

// Phase 1: lower-bound table. lb[r] = first nnz index with bid >= r,
// lb[BATCH] = nnz. Every entry written every launch (ws is poisoned 0xAA,
// so no sentinel semantics allowed). Row r segment = [lb[r], lb[r+1]).
__global__ __launch_bounds__(256) void seg_lb(
    const int* __restrict__ bids, int* __restrict__ lb, int nnz)
{
    int i = blockIdx.x * blockDim.x + threadIdx.x;
    if (i >= nnz) return;
    int b  = bids[i];
    int bp = (i == 0) ? -1 : bids[i - 1];
    for (int r = bp + 1; r <= b; ++r) lb[r] = i;   // i==0 covers 0..bids[0]
    if (i == nnz - 1)
        for (int r = b + 1; r <= BATCH; ++r) lb[r] = nnz;
}

// Phase 2: one 256-thread block (4 waves) per output row. Each wave takes
// 64-nnz windows at stride 256 within the row's segment: meta (fid,val)
// loaded coalesced (one nnz/lane) and broadcast via __shfl; 16-lane groups
// gather one 256 B embedding row per slot as float4/lane, G=8 gathers in
// flight per lane. Per-wave partials reduced by 2 shfl_xor stages, then
// the 4 waves combine through LDS. No atomics.
__global__ __launch_bounds__(256, 6) void fm_row(
    const float4* __restrict__ emb4,   // [VOCAB*16] float4
    const float*  __restrict__ vals,
    const int*    __restrict__ fids,
    const int*    __restrict__ lb,     // [BATCH+1]
    float4*       __restrict__ out4)   // [BATCH*16] float4
{
    const int r    = blockIdx.x;
    const int wv   = threadIdx.x >> 6;  // wave within block (0..3)
    const int lane = threadIdx.x & 63;
    const int grp  = lane >> 4;   // which nnz slot within a 4-nnz step
    const int sub  = lane & 15;   // which float4 of the 64-dim row

    const int s0 = lb[r];
    const int s1 = lb[r + 1];

    float4 s = make_float4(0.f, 0.f, 0.f, 0.f);
    float4 q = make_float4(0.f, 0.f, 0.f, 0.f);

    for (int w0 = s0 + (wv << 6); w0 < s1; w0 += 4 * 64) {
        // coalesced meta for this window (one nnz per lane, clamped)
        int   idx   = w0 + lane;
        int   c     = min(idx, s1 - 1);
        int   f_cur = fids[c];
        float v_cur = (idx < s1) ? vals[idx] : 0.f;
        const int lim = min(64, s1 - w0);
        #pragma unroll
        for (int b = 0; b < 2; ++b) {
            if (b * 32 >= lim) break;
            float4 e[G]; float vv[G];
            #pragma unroll
            for (int g = 0; g < G; ++g) {
                int j  = b * 32 + 4 * g + grp;       // nnz slot in window
                int f  = __shfl(f_cur, j);
                vv[g]  = __shfl(v_cur, j);
                e[g]   = emb4[(size_t)f * 16 + sub]; // 8 gathers in flight
            }
            #pragma unroll
            for (int g = 0; g < G; ++g) {
                float ax = vv[g] * e[g].x, ay = vv[g] * e[g].y;
                float az = vv[g] * e[g].z, aw = vv[g] * e[g].w;
                s.x += ax;      s.y += ay;      s.z += az;      s.w += aw;
                q.x += ax * ax; q.y += ay * ay; q.z += az * az; q.w += aw * aw;
            }
        }
    }

    // combine the 4 group partials within the wave (lane bits 4,5)
    #pragma unroll
    for (int m = 16; m <= 32; m <<= 1) {
        s.x += __shfl_xor(s.x, m); s.y += __shfl_xor(s.y, m);
        s.z += __shfl_xor(s.z, m); s.w += __shfl_xor(s.w, m);
        q.x += __shfl_xor(q.x, m); q.y += __shfl_xor(q.y, m);
        q.z += __shfl_xor(q.z, m); q.w += __shfl_xor(q.w, m);
    }

    // combine the 4 wave partials through LDS
    __shared__ float4 sb[4][16], qb[4][16];
    if (grp == 0) { sb[wv][sub] = s; qb[wv][sub] = q; }
    __syncthreads();
    if (threadIdx.x < 16) {
        float4 S = sb[0][lane], Q = qb[0][lane];
        #pragma unroll
        for (int w = 1; w < 4; ++w) {
            float4 a = sb[w][lane], c2 = qb[w][lane];
            S.x += a.x;  S.y += a.y;  S.z += a.z;  S.w += a.w;
            Q.x += c2.x; Q.y += c2.y; Q.z += c2.z; Q.w += c2.w;
        }
        float4 o;
        o.x = 0.5f * (S.x * S.x - Q.x);
        o.y = 0.5f * (S.y * S.y - Q.y);
        o.z = 0.5f * (S.z * S.z - Q.z);
        o.w = 0.5f * (S.w * S.w - Q.w);
        out4[r * 16 + lane] = o;
    }
}

extern "C" void kernel_launch(void* const* d_in, const int* in_sizes, int n_in,
                              void* d_out, int out_size, void* d_ws, size_t ws_size,
                              hipStream_t stream) {
    const float4* emb4 = (const float4*)d_in[0];
    const float*  vals = (const float*)d_in[1];
    const int*    bids = (const int*)d_in[2];
    const int*    fids = (const int*)d_in[3];
    float4*       out4 = (float4*)d_out;
    const int nnz = in_sizes[1];

    int* lb = (int*)d_ws;   // BATCH+1 ints, fully rewritten each launch

    seg_lb<<<dim3((nnz + 255) / 256), dim3(256), 0, stream>>>(bids, lb, nnz);

    fm_row<<<dim3(BATCH), dim3(256), 0, stream>>>(
        emb4, vals, fids, lb, out4);
}